// Round 1
// baseline (540.017 us; speedup 1.0000x reference)
//
#include <hip/hip_runtime.h>
#include <math.h>

#define K_DIM 4096
#define N_DIM 256
#define M_DIM 16384
#define NSTAGES 128        // K / 32
#define ABUF 4096          // one A stage buffer: 32 rows * 128 B (hi|lo granules)

typedef short bf8v __attribute__((ext_vector_type(8)));
typedef float f32x16 __attribute__((ext_vector_type(16)));
typedef unsigned short us8 __attribute__((ext_vector_type(8)));

union AB { unsigned u[4]; bf8v v; };

// RNE pack of two f32 -> two bf16 (lo = src0). gfx950 HW instr; no builtin (m240).
__device__ __forceinline__ unsigned cvt_pk(float a, float b) {
    unsigned r;
    asm("v_cvt_pk_bf16_f32 %0, %1, %2" : "=v"(r) : "v"(a), "v"(b));
    return r;
}

// ---------------- beta kernel (unchanged, harness-verified) ----------------
// beta[j] = bias[j] + (1/4096) * prod_{d,k} cos^2(uw[d, j, k])
__global__ void beta_kernel(const float* __restrict__ uw,
                            const float* __restrict__ bias,
                            float* __restrict__ beta) {
    int j = threadIdx.x;
    float p = 1.0f / 4096.0f;
    #pragma unroll
    for (int d = 0; d < 9; ++d) {
        const float* a = uw + (size_t)d * (K_DIM * N_DIM) + (size_t)j * N_DIM;
        #pragma unroll
        for (int k = 0; k < 3; ++k) {
            float c = cosf(a[k]);
            p *= c * c;
        }
    }
    beta[j] = bias[j] + p;
}

// ---------------- W pretile into per-lane MFMA fragment order --------------
// Bt granule layout (16 B = 8 bf16): [s][w(8)][h(2: hi/lo)][ks(2)][lane(64)]
// granule(s,w,h,ks,l)[j] = split_h( W[s*32 + ks*16 + (l>>5)*8 + j][w*32 + (l&31)] )
// -> GEMM loads B fragments as coalesced 1-KB global loads, no LDS for B.
__global__ void pretile_w_kernel(const float* __restrict__ W,
                                 unsigned short* __restrict__ Bt) {
    const int s = blockIdx.x;     // 0..127
    const int t = threadIdx.x;    // 0..255
    #pragma unroll
    for (int g = 0; g < 8; ++g) {
        const int G  = g * 256 + t;       // 0..2047
        const int w  = G >> 8;
        const int h  = (G >> 7) & 1;
        const int ks = (G >> 6) & 1;
        const int l  = G & 63;
        const int n  = w * 32 + (l & 31);
        const int k0 = s * 32 + ks * 16 + (l >> 5) * 8;
        unsigned short o8[8];
        #pragma unroll
        for (int j = 0; j < 8; ++j) {
            float f = W[(size_t)(k0 + j) * N_DIM + n];
            unsigned u = __float_as_uint(f);
            unsigned hh = u + 0x7fffu + ((u >> 16) & 1u);     // RNE bf16 hi
            if (h == 0) {
                o8[j] = (unsigned short)(hh >> 16);
            } else {
                float r = f - __uint_as_float(hh & 0xffff0000u);  // exact residual
                unsigned ur = __float_as_uint(r);
                o8[j] = (unsigned short)((ur + 0x7fffu + ((ur >> 16) & 1u)) >> 16);
            }
        }
        *(us8*)&Bt[((size_t)s * 2048 + G) * 8] = *(us8*)&o8[0];
    }
}

// ---------------- GEMM + tanh ----------------
// out[m,n] = tanh(sum_k x[m,k]*W[k,n] + beta[n]); 3-term bf16 split.
// Block = 32 rows x 256 cols, 512 thr = 8 waves, wave-tile 32x32 (wave w -> n-strip).
// mfma_f32_32x32x16_bf16: A row=l&31, k=(l>>5)*8+j; B col=l&31, same k;
// D col=l&31, row=(r&3)+8*(r>>2)+4*(l>>5)  [m74/m101].
// A: reg-staged fp32 (coalesced float2/thread) -> cvt_pk hi/lo -> LDS, XOR-swizzled
//    granules (g ^= row&7): frag ds_read_b128 is bank-conflict-free (1 KB / 8 cyc).
// B: direct global->VGPR from pretiled image (L2-resident, 4 x 1 KB coalesced).
// Double-buffered LDS (8 KB total), 1 lgkmcnt(0)+s_barrier per stage, no vmcnt asm:
// all global loads are compiler-tracked. 512 blocks -> 2 blocks/CU, 4 waves/SIMD.
__global__ __launch_bounds__(512, 4)
void gemm_tanh_kernel(const float* __restrict__ X,
                      const unsigned short* __restrict__ Bt,
                      const float* __restrict__ beta,
                      float* __restrict__ out) {
    __shared__ __align__(16) char lds[2 * ABUF];

    const int t = threadIdx.x;
    const int lane = t & 63;
    const int w = t >> 6;          // wave id = n-strip (0..7)
    const int l31 = lane & 31;
    const int lh = lane >> 5;
    const int m0 = blockIdx.x * 32;

    // A staging: thread -> (row = t>>4, kpair = t&15): elements k = 2*kp, 2*kp+1.
    // Per wave: 4 rows x 128 B contiguous -> perfect coalescing; each element
    // loaded & converted exactly once per block (and each row once on the GPU).
    const int srow = t >> 4;
    const int kp = t & 15;
    const float* pa = X + (size_t)(m0 + srow) * K_DIM + kp * 2;
    // LDS image: row stride 128 B = 8 granules x 16 B: g 0..3 = hi khalf, 4..7 = lo.
    // Swizzle: g' = g ^ (row&7).
    const int whi_off = srow * 128 + ((((kp >> 2)    ) ^ (srow & 7)) << 4) + (kp & 3) * 4;
    const int wlo_off = srow * 128 + ((((kp >> 2) + 4) ^ (srow & 7)) << 4) + (kp & 3) * 4;

    // Frag reads: lane l -> row=l31; hi ks0: g=lh, hi ks1: g=2+lh, lo: +4.
    const int fx = (l31 & 7) << 4;
    const int rb = l31 * 128;
    const int ro_h0 = rb + (((0 + lh) << 4) ^ fx);
    const int ro_h1 = rb + (((2 + lh) << 4) ^ fx);
    const int ro_l0 = rb + (((4 + lh) << 4) ^ fx);
    const int ro_l1 = rb + (((6 + lh) << 4) ^ fx);

    const unsigned short* pb = Bt + w * 2048 + lane * 8;

    f32x16 acc = (f32x16)(0.0f);
    float2 araw;
    AB bA[4], bB[4];

#define LOADB(dst, sidx) { \
    const unsigned short* p_ = pb + (size_t)(sidx) * 16384; \
    dst[0].v = *(const bf8v*)(p_);          /* hi ks0 */ \
    dst[1].v = *(const bf8v*)(p_ + 512);    /* hi ks1 */ \
    dst[2].v = *(const bf8v*)(p_ + 1024);   /* lo ks0 */ \
    dst[3].v = *(const bf8v*)(p_ + 1536); } /* lo ks1 */

#define CVTWR(ar, NB) { \
    unsigned hp_ = cvt_pk(ar.x, ar.y); \
    float r0_ = ar.x - __uint_as_float(hp_ << 16);          /* exact residuals */ \
    float r1_ = ar.y - __uint_as_float(hp_ & 0xffff0000u); \
    unsigned lp_ = cvt_pk(r0_, r1_); \
    *(unsigned*)(lds + (NB) + whi_off) = hp_; \
    *(unsigned*)(lds + (NB) + wlo_off) = lp_; }

#define MFMA(a, b) acc = __builtin_amdgcn_mfma_f32_32x32x16_bf16((a), (b), acc, 0, 0, 0)

    // Prologue: stage s=0 into buf0; prefetch raw A(1) and B(0).
    {
        float2 a0 = *(const float2*)pa;
        CVTWR(a0, 0);
        araw = *(const float2*)(pa + 32);
        LOADB(bA, 0);
        asm volatile("s_waitcnt lgkmcnt(0)\n\ts_barrier" ::: "memory");
    }

    // Body s: compute buf[CB] with B regs BCUR; meanwhile cvt+write A(s+1) into
    // buf[NB], load raw A(s+2), load B(s+1) into BNXT. One barrier per stage.
#define BODY(s, CB, NB, BCUR, BNXT) { \
    CVTWR(araw, NB); \
    araw = *(const float2*)(pa + (size_t)(((s) + 2) & 127) * 32); \
    LOADB(BNXT, ((s) + 1) & 127); \
    AB ah0, ah1, al0, al1; \
    ah0.v = *(const bf8v*)(lds + (CB) + ro_h0); \
    ah1.v = *(const bf8v*)(lds + (CB) + ro_h1); \
    al0.v = *(const bf8v*)(lds + (CB) + ro_l0); \
    al1.v = *(const bf8v*)(lds + (CB) + ro_l1); \
    MFMA(ah0.v, BCUR[0].v); \
    MFMA(al0.v, BCUR[0].v); \
    MFMA(ah0.v, BCUR[2].v); \
    MFMA(ah1.v, BCUR[1].v); \
    MFMA(al1.v, BCUR[1].v); \
    MFMA(ah1.v, BCUR[3].v); \
    asm volatile("s_waitcnt lgkmcnt(0)\n\ts_barrier" ::: "memory"); \
}

    for (int s = 0; s < NSTAGES; s += 2) {
        BODY(s,     0,    ABUF, bA, bB);
        BODY(s + 1, ABUF, 0,    bB, bA);
    }

#undef BODY
#undef MFMA
#undef CVTWR
#undef LOADB

    // Epilogue: D col = l&31, row = (r&3) + 8*(r>>2) + 4*lh.
    const float bet = beta[w * 32 + l31];
    float* po = out + (size_t)(m0 + 4 * lh) * N_DIM + w * 32 + l31;
    #pragma unroll
    for (int r = 0; r < 16; ++r) {
        const int row = (r & 3) + 8 * (r >> 2);
        po[(size_t)row * N_DIM] = tanhf(acc[r] + bet);
    }
}

extern "C" void kernel_launch(void* const* d_in, const int* in_sizes, int n_in,
                              void* d_out, int out_size, void* d_ws, size_t ws_size,
                              hipStream_t stream) {
    const float* x    = (const float*)d_in[0];
    const float* uw   = (const float*)d_in[1];
    const float* W    = (const float*)d_in[2];
    const float* bias = (const float*)d_in[3];
    float* out = (float*)d_out;

    // workspace: Bt pretiled (4 MB) | beta (1 KB)
    char* ws = (char*)d_ws;
    unsigned short* bt = (unsigned short*)ws;
    float* beta = (float*)(ws + (size_t)4 * 1024 * 1024);

    pretile_w_kernel<<<dim3(NSTAGES), 256, 0, stream>>>(W, bt);
    beta_kernel<<<1, 256, 0, stream>>>(uw, bias, beta);

    gemm_tanh_kernel<<<dim3(M_DIM / 32), 512, 0, stream>>>(x, bt, beta, out);
}